// Round 18
// baseline (226.356 us; speedup 1.0000x reference)
//
#include <hip/hip_runtime.h>
#include <math.h>

typedef __attribute__((ext_vector_type(4))) float f32x4;
typedef __attribute__((ext_vector_type(8))) short s16x8;
typedef __attribute__((ext_vector_type(4))) unsigned int u32x4;
typedef unsigned short ushort_t;

#define HW   1024
#define C_IN 768
#define B_N  8

__device__ inline ushort_t f2bf(float f) {
    unsigned u = __builtin_bit_cast(unsigned, f);
    unsigned r = u + 0x7FFFu + ((u >> 16) & 1u);
    return (ushort_t)(r >> 16);
}
__device__ inline float bf2f(short s) {
    return __builtin_bit_cast(float, ((unsigned)(ushort_t)s) << 16);
}
__device__ inline void glds16(const void* g, void* l) {
    __builtin_amdgcn_global_load_lds(
        (const __attribute__((address_space(1))) unsigned*)g,
        (__attribute__((address_space(3))) unsigned*)l, 16, 0, 0);
}

// ---------------------------------------------------------------------------
// Fused prepack: [0,1536) xt transpose; [1536,2112) proj A-frags; [2112,2220)
// offset/mask A-frags. One launch instead of three.
// ---------------------------------------------------------------------------
__global__ __launch_bounds__(256) void prepack_all(
    const float* __restrict__ x, ushort_t* __restrict__ xt,
    const float* __restrict__ pw, ushort_t* __restrict__ A,
    const float* __restrict__ offw, const float* __restrict__ mskw,
    ushort_t* __restrict__ A2)
{
    __shared__ ushort_t sh[9344];          // 18688 B, shared by branches
    int bid = blockIdx.x;
    int t = threadIdx.x;

    if (bid < 1536) {                      // ---- xt transpose ----
        ushort_t (*tile)[66] = (ushort_t (*)[66])sh;
        int b  = bid / 192;
        int r  = bid % 192;
        int cg = r / 16, pg = r % 16;
        int c0 = cg * 64, p0 = pg * 64;
#pragma unroll
        for (int i = 0; i < 16; ++i) {
            int idx = t + i * 256;
            int cr = idx >> 6, col = idx & 63;
            tile[cr][col] = f2bf(x[(((size_t)b * C_IN + c0 + cr) << 10) + p0 + col]);
        }
        __syncthreads();
#pragma unroll
        for (int i = 0; i < 16; ++i) {
            int idx = t + i * 256;
            int pr = idx >> 6, col = idx & 63;
            xt[((size_t)(b << 10) + p0 + pr) * C_IN + c0 + col] = tile[col][pr];
        }
    } else if (bid < 2112) {               // ---- proj_w A-frags ----
        ushort_t (*tile)[584] = (ushort_t (*)[584])sh;
        int pb = bid - 1536;               // 48 mf x 12 cblk
        int mf = pb / 12, cblk = pb - mf * 12;
        const float* src = pw + (size_t)mf * 16 * 6912 + cblk * 576;
#pragma unroll
        for (int i = 0; i < 36; ++i) {
            int f = i * 256 + t;
            int orow = f / 576, col = f - orow * 576;
            tile[orow][col] = f2bf(src[(size_t)orow * 6912 + col]);
        }
        __syncthreads();
        int lane = t & 63, fi0 = t >> 6;
        for (int it = 0; it < 5; ++it) {
            int fidx = it * 4 + fi0;       // 18 frags: tap*2 + half
            if (fidx < 18) {
                int tap = fidx >> 1, half = fidx & 1;
                int s = tap * 24 + cblk * 2 + half;
                int cl0 = half * 32 + ((lane >> 4) << 3);
                s16x8 pk;
#pragma unroll
                for (int e = 0; e < 8; ++e)
                    pk[e] = (short)tile[lane & 15][(cl0 + e) * 9 + tap];
                *(s16x8*)(A + ((size_t)(s * 48 + mf) * 64 + lane) * 8) = pk;
            }
        }
    } else {                               // ---- offset/mask A-frags ----
        int tt = (bid - 2112) * 256 + t;   // 216*2*64 threads
        int lane = tt & 63;
        int smi  = tt >> 6;
        int s  = smi >> 1, mf = smi & 1;
        int oc = mf * 16 + (lane & 15);
        int k0 = s * 32 + ((lane >> 4) << 3);
        int tap = k0 / 768;
        int c   = k0 - tap * 768;
        s16x8 pk;
#pragma unroll
        for (int e = 0; e < 8; ++e) pk[e] = 0;
        if (oc < 27) {
            const float* src = (oc < 18)
                ? offw + ((size_t)oc        * 768 + c) * 9 + tap
                : mskw + ((size_t)(oc - 18) * 768 + c) * 9 + tap;
#pragma unroll
            for (int e = 0; e < 8; ++e) pk[e] = (short)f2bf(src[e * 9]);
        }
        *(s16x8*)(A2 + (size_t)smi * 512 + lane * 8) = pk;
    }
}

// ---------------------------------------------------------------------------
// Offset/mask conv: LDS-free MFMA GEMM, 4-way K-split (16 waves, no in-loop
// barriers; single end reduction).
// ---------------------------------------------------------------------------
__global__ __launch_bounds__(1024) void offmask_mfma(
    const ushort_t* __restrict__ xt, const ushort_t* __restrict__ A2,
    const float* __restrict__ offb, const float* __restrict__ mbias,
    float* __restrict__ offs, float* __restrict__ maskb)
{
    __shared__ f32x4 red[16][64];
    int bid = blockIdx.x;               // b*32 + pt
    int b = bid >> 5, pt = bid & 31;
    int p0 = pt << 5;
    int t = threadIdx.x, lane = t & 63, wv = t >> 6;
    int kq = wv >> 2, quad = wv & 3;
    int mf = quad >> 1, nf = quad & 1;
    int q = lane >> 4;
    int px = p0 + nf * 16 + (lane & 15);
    int h = px >> 5, w = px & 31;
    const char* xb = (const char*)xt + (size_t)b * (HW * 1536);
    f32x4 acc = (f32x4){0.f, 0.f, 0.f, 0.f};

    int s0 = kq * 54;
    for (int s = s0; s < s0 + 54; ++s) {
        int tap = s / 24, cs = s - tap * 24;
        int yy = h + tap / 3 - 1, xx = w + tap % 3 - 1;
        bool ok = (yy >= 0 && yy < 32 && xx >= 0 && xx < 32);
        int pos = ok ? (yy * 32 + xx) : 0;
        const char* bp = xb + (size_t)pos * 1536 + cs * 64 + q * 16;
        s16x8 bf;
        if (ok) bf = *(const s16x8*)bp;
        else    bf = (s16x8){0, 0, 0, 0, 0, 0, 0, 0};
        s16x8 af = *(const s16x8*)(A2 + ((size_t)(s * 2 + mf) * 64 + lane) * 8);
        acc = __builtin_amdgcn_mfma_f32_16x16x32_bf16(af, bf, acc, 0, 0, 0);
    }
    red[wv][lane] = acc;
    __syncthreads();
    if (wv < 4) {
        f32x4 r1 = red[wv + 4][lane];
        f32x4 r2 = red[wv + 8][lane];
        f32x4 r3 = red[wv + 12][lane];
        acc += r1; acc += r2; acc += r3;
#pragma unroll
        for (int r = 0; r < 4; ++r) {
            int oc = mf * 16 + ((lane >> 4) << 2) + r;
            if (oc < 18) {
                float v = acc[r] + offb[oc];
                v = fminf(fmaxf(v, -8.f), 8.f);        // max_off = 32//4
                offs[((b * 18 + oc) << 10) + px] = v;
            } else if (oc < 27) {
                float v = acc[r] + mbias[oc - 18];
                maskb[((b * 9 + oc - 18) << 10) + px] = 2.f / (1.f + expf(-v));
            }
        }
    }
}

// ---------------------------------------------------------------------------
// Split kernel 1: build the bilinear-sampled tensor ONCE (1x replication),
// directly in MFMA B-fragment layout. b = bid&7 -> XCD keeps xt slab L2-local.
// ---------------------------------------------------------------------------
__global__ __launch_bounds__(512) void sample_pack(
    const ushort_t* __restrict__ xt,
    const float* __restrict__ offs, const float* __restrict__ maskb,
    ushort_t* __restrict__ Bp)
{
    __shared__ float4 mw[9][16];
    __shared__ int4   mi[9][16];
    int bid = blockIdx.x;                 // pxg*8 + b  (b = XCD slab)
    int b = bid & 7, pxg = bid >> 3;
    int px0 = pxg << 4;
    int t = threadIdx.x;

    if (t < 144) {
        int tap = t >> 4, pxl = t & 15;
        int px = px0 + pxl, h = px >> 5, w = px & 31;
        float dy = offs[((b * 18 + 2 * tap) << 10) + px];
        float dx = offs[((b * 18 + 2 * tap + 1) << 10) + px];
        float m  = maskb[((b * 9 + tap) << 10) + px];
        float ys = dy + (float)(h + tap / 3 - 1);
        float xs = dx + (float)(w + tap % 3 - 1);
        float fy = floorf(ys), fx = floorf(xs);
        float wy = ys - fy, wx = xs - fx;
        int iy0 = (int)fy, ix0 = (int)fx;
        int iy1 = iy0 + 1, ix1 = ix0 + 1;
        float vy0 = (iy0 >= 0 && iy0 < 32) ? 1.f : 0.f;
        float vy1 = (iy1 >= 0 && iy1 < 32) ? 1.f : 0.f;
        float vx0 = (ix0 >= 0 && ix0 < 32) ? 1.f : 0.f;
        float vx1 = (ix1 >= 0 && ix1 < 32) ? 1.f : 0.f;
        int cy0 = min(max(iy0, 0), 31), cx0 = min(max(ix0, 0), 31);
        int cy1 = min(max(iy1, 0), 31), cx1 = min(max(ix1, 0), 31);
        float4 wv4;
        wv4.x = (1.f - wy) * (1.f - wx) * m * vy0 * vx0;
        wv4.y = (1.f - wy) * wx         * m * vy0 * vx1;
        wv4.z = wy         * (1.f - wx) * m * vy1 * vx0;
        wv4.w = wy         * wx         * m * vy1 * vx1;
        mw[tap][pxl] = wv4;
        mi[tap][pxl] = make_int4((cy0 * 32 + cx0) * 1536, (cy0 * 32 + cx1) * 1536,
                                 (cy1 * 32 + cx0) * 1536, (cy1 * 32 + cx1) * 1536);
    }
    __syncthreads();

    int lane = t & 63, wv = t >> 6;
    int pxl = lane & 15, ko = lane >> 4;
    const char* xb = (const char*)xt + (size_t)b * (HW * 1536);

    for (int s = wv; s < 216; s += 8) {
        int tap = s / 24, cq = s - tap * 24;
        float4 w4 = mw[tap][pxl];
        int4  i4 = mi[tap][pxl];
        const char* base = xb + cq * 64 + ko * 16;
        s16x8 g0 = *(const s16x8*)(base + i4.x);
        s16x8 g1 = *(const s16x8*)(base + i4.y);
        s16x8 g2 = *(const s16x8*)(base + i4.z);
        s16x8 g3 = *(const s16x8*)(base + i4.w);
        u32x4 bw;
#pragma unroll
        for (int e2 = 0; e2 < 4; ++e2) {
            float v0 = w4.x * bf2f(g0[2 * e2])     + w4.y * bf2f(g1[2 * e2])
                     + w4.z * bf2f(g2[2 * e2])     + w4.w * bf2f(g3[2 * e2]);
            float v1 = w4.x * bf2f(g0[2 * e2 + 1]) + w4.y * bf2f(g1[2 * e2 + 1])
                     + w4.z * bf2f(g2[2 * e2 + 1]) + w4.w * bf2f(g3[2 * e2 + 1]);
            unsigned rr;
            asm("v_cvt_pk_bf16_f32 %0, %1, %2" : "=v"(rr) : "v"(v0), "v"(v1));
            bw[e2] = rr;
        }
        *(u32x4*)(Bp + ((size_t)(s * 8 + b) * 64 + pxg) * 512 + lane * 8) = bw;
    }
}

// ---------------------------------------------------------------------------
// Split kernel 2 (v5): A via LDS (24KB/phase, dbuf 48KB), B DIRECT TO REGS
// from the pre-packed Bp fragments (depth-1 prefetch: BLOAD(p+1) issued at
// phase-p start, consumed after the barrier). Removes 64KB/phase of LDS
// reads (the 4x-shared B re-reads) -> LDS-read time ~1900 -> ~1130 cyc/phase.
// Schedule identical to the proven R12 loop: 108 phases, one
// vmcnt(0)+lgkmcnt(0)+barrier each.
// ---------------------------------------------------------------------------
__global__ __launch_bounds__(512, 4) void deform_gemm_lds(
    const ushort_t* __restrict__ Amat, const ushort_t* __restrict__ Bp,
    float* __restrict__ y)
{
    __shared__ __align__(16) char Sbuf[2][24576];   // A only, 48 KiB

    int id = blockIdx.x;                  // 512 = 8b x 16pxt x 4otile
    int b = id & 7;                       // b == XCD slab locality
    int pxt = (id >> 3) & 15;
    int otile = id >> 7;
    int p0 = pxt << 6;
    int t = threadIdx.x, lane = t & 63, wv = t >> 6;
    int wm = wv >> 1, wn = wv & 1;

    f32x4 acc[3][2];
#pragma unroll
    for (int f = 0; f < 3; ++f)
#pragma unroll
        for (int n = 0; n < 2; ++n) acc[f][n] = (f32x4){0.f, 0.f, 0.f, 0.f};

    s16x8 ba00, ba01, ba10, ba11;         // B regs, even phases
    s16x8 bb00, bb01, bb10, bb11;         // B regs, odd phases

#define STAGE_A(BUF, P) do {                                                \
    int s0_ = 2 * (P);                                                      \
    _Pragma("unroll")                                                       \
    for (int i_ = 0; i_ < 3; ++i_) {                                        \
        int c_ = wv * 3 + i_;                                               \
        int kk_ = c_ / 12, f_ = c_ - kk_ * 12;                              \
        const char* src_ = (const char*)Amat +                              \
            (((size_t)(s0_ + kk_) * 48 + otile * 12 + f_) << 10);           \
        glds16(src_ + lane * 16, &Sbuf[BUF][c_ << 10]);                     \
    }                                                                       \
} while (0)

#define BLOAD(B00, B01, B10, B11, P) do {                                   \
    int s0_ = 2 * (P);                                                      \
    const char* p0_ = (const char*)Bp +                                     \
        ((((size_t)s0_ * 8 + b) * 64 + pxt * 4 + wn * 2) << 10) + lane * 16; \
    B00 = *(const s16x8*)(p0_);                                             \
    B01 = *(const s16x8*)(p0_ + 1024);                                      \
    const char* p1_ = (const char*)Bp +                                     \
        ((((size_t)(s0_ + 1) * 8 + b) * 64 + pxt * 4 + wn * 2) << 10) + lane * 16; \
    B10 = *(const s16x8*)(p1_);                                             \
    B11 = *(const s16x8*)(p1_ + 1024);                                      \
} while (0)

#define MFMA_PHASE(BUF, B00, B01, B10, B11) do {                            \
    {                                                                       \
        const char* ab_ = &Sbuf[BUF][(wm * 3) << 10] + lane * 16;           \
        s16x8 a0_ = *(const s16x8*)(ab_);                                   \
        s16x8 a1_ = *(const s16x8*)(ab_ + 1024);                            \
        s16x8 a2_ = *(const s16x8*)(ab_ + 2048);                            \
        acc[0][0] = __builtin_amdgcn_mfma_f32_16x16x32_bf16(a0_, B00, acc[0][0], 0, 0, 0); \
        acc[0][1] = __builtin_amdgcn_mfma_f32_16x16x32_bf16(a0_, B01, acc[0][1], 0, 0, 0); \
        acc[1][0] = __builtin_amdgcn_mfma_f32_16x16x32_bf16(a1_, B00, acc[1][0], 0, 0, 0); \
        acc[1][1] = __builtin_amdgcn_mfma_f32_16x16x32_bf16(a1_, B01, acc[1][1], 0, 0, 0); \
        acc[2][0] = __builtin_amdgcn_mfma_f32_16x16x32_bf16(a2_, B00, acc[2][0], 0, 0, 0); \
        acc[2][1] = __builtin_amdgcn_mfma_f32_16x16x32_bf16(a2_, B01, acc[2][1], 0, 0, 0); \
    }                                                                       \
    {                                                                       \
        const char* ab_ = &Sbuf[BUF][(12 + wm * 3) << 10] + lane * 16;      \
        s16x8 a0_ = *(const s16x8*)(ab_);                                   \
        s16x8 a1_ = *(const s16x8*)(ab_ + 1024);                            \
        s16x8 a2_ = *(const s16x8*)(ab_ + 2048);                            \
        acc[0][0] = __builtin_amdgcn_mfma_f32_16x16x32_bf16(a0_, B10, acc[0][0], 0, 0, 0); \
        acc[0][1] = __builtin_amdgcn_mfma_f32_16x16x32_bf16(a0_, B11, acc[0][1], 0, 0, 0); \
        acc[1][0] = __builtin_amdgcn_mfma_f32_16x16x32_bf16(a1_, B10, acc[1][0], 0, 0, 0); \
        acc[1][1] = __builtin_amdgcn_mfma_f32_16x16x32_bf16(a1_, B11, acc[1][1], 0, 0, 0); \
        acc[2][0] = __builtin_amdgcn_mfma_f32_16x16x32_bf16(a2_, B10, acc[2][0], 0, 0, 0); \
        acc[2][1] = __builtin_amdgcn_mfma_f32_16x16x32_bf16(a2_, B11, acc[2][1], 0, 0, 0); \
    }                                                                       \
} while (0)

    // prologue
    STAGE_A(0, 0);
    BLOAD(ba00, ba01, ba10, ba11, 0);
    asm volatile("s_waitcnt vmcnt(0)" ::: "memory");
    __builtin_amdgcn_s_barrier();

    for (int pp = 0; pp < 54; ++pp) {
        int pe = 2 * pp;
        // pe+1 <= 107 always
        STAGE_A(1, pe + 1);
        BLOAD(bb00, bb01, bb10, bb11, pe + 1);
        __builtin_amdgcn_s_setprio(1);
        MFMA_PHASE(0, ba00, ba01, ba10, ba11);
        __builtin_amdgcn_s_setprio(0);
        asm volatile("s_waitcnt vmcnt(0) lgkmcnt(0)" ::: "memory");
        __builtin_amdgcn_s_barrier();

        int po = pe + 1;
        if (po + 1 < 108) {
            STAGE_A(0, po + 1);
            BLOAD(ba00, ba01, ba10, ba11, po + 1);
        }
        __builtin_amdgcn_s_setprio(1);
        MFMA_PHASE(1, bb00, bb01, bb10, bb11);
        __builtin_amdgcn_s_setprio(0);
        asm volatile("s_waitcnt vmcnt(0) lgkmcnt(0)" ::: "memory");
        __builtin_amdgcn_s_barrier();
    }

    // epilogue (no bias: per-channel bias cancels in batch-norm)
    int pxo = p0 + wn * 32 + (lane & 15);
    int obase = otile * 192 + wm * 48;
#pragma unroll
    for (int f = 0; f < 3; ++f) {
        int orow = obase + f * 16 + ((lane >> 4) << 2);
#pragma unroll
        for (int r = 0; r < 4; ++r) {
            size_t rowoff = ((size_t)(b * 768 + orow + r) << 10);
            y[rowoff + pxo]      = acc[f][0][r];
            y[rowoff + pxo + 16] = acc[f][1][r];
        }
    }
#undef STAGE_A
#undef BLOAD
#undef MFMA_PHASE
}

// ---------------------------------------------------------------------------
// FALLBACK (small ws): fused deform GEMM — the proven R5 structure.
// ---------------------------------------------------------------------------
__global__ __launch_bounds__(512, 4) void deform_mfma_fused(
    const ushort_t* __restrict__ xt, const ushort_t* __restrict__ Amat,
    const float* __restrict__ offs, const float* __restrict__ maskb,
    float* __restrict__ y)
{
    __shared__ float4 meta_w[576];
    __shared__ int4   meta_i[576];
    __shared__ __align__(16) ushort_t Bs[2][64][64];

    int id = blockIdx.x;
    int b = id & 7;
    int pxt = (id >> 3) & 15;
    int otile = id >> 7;
    int p0 = pxt << 6;
    int t = threadIdx.x, lane = t & 63, wv = t >> 6;
    int wm = wv >> 1, wn = wv & 1;
    int q4 = lane >> 4;

    int bpx = wv * 8 + (lane >> 3);
    int oct = lane & 7;
    const int wchunk = (oct ^ (bpx & 7)) * 8;

    for (int i = t; i < 576; i += 512) {
        int k = i >> 6, j = i & 63;
        int hw = p0 + j, h = hw >> 5, w = hw & 31;
        float dy = offs[((b * 18 + 2 * k) << 10) + hw];
        float dx = offs[((b * 18 + 2 * k + 1) << 10) + hw];
        float m  = maskb[((b * 9 + k) << 10) + hw];
        float ys = dy + (float)(h + k / 3 - 1);
        float xs = dx + (float)(w + k % 3 - 1);
        float fy = floorf(ys), fx = floorf(xs);
        float wy = ys - fy, wx = xs - fx;
        int iy0 = (int)fy, ix0 = (int)fx;
        int iy1 = iy0 + 1, ix1 = ix0 + 1;
        float vy0 = (iy0 >= 0 && iy0 < 32) ? 1.f : 0.f;
        float vy1 = (iy1 >= 0 && iy1 < 32) ? 1.f : 0.f;
        float vx0 = (ix0 >= 0 && ix0 < 32) ? 1.f : 0.f;
        float vx1 = (ix1 >= 0 && ix1 < 32) ? 1.f : 0.f;
        int cy0 = min(max(iy0, 0), 31), cx0 = min(max(ix0, 0), 31);
        int cy1 = min(max(iy1, 0), 31), cx1 = min(max(ix1, 0), 31);
        float4 wv4;
        wv4.x = (1.f - wy) * (1.f - wx) * m * vy0 * vx0;
        wv4.y = (1.f - wy) * wx         * m * vy0 * vx1;
        wv4.z = wy         * (1.f - wx) * m * vy1 * vx0;
        wv4.w = wy         * wx         * m * vy1 * vx1;
        meta_w[i] = wv4;
        meta_i[i] = make_int4((cy0 * 32 + cx0) * 1536, (cy0 * 32 + cx1) * 1536,
                              (cy1 * 32 + cx0) * 1536, (cy1 * 32 + cx1) * 1536);
    }
    asm volatile("s_waitcnt lgkmcnt(0)" ::: "memory");
    __builtin_amdgcn_s_barrier();

    f32x4 acc[3][2];
#pragma unroll
    for (int f = 0; f < 3; ++f)
#pragma unroll
        for (int n = 0; n < 2; ++n) acc[f][n] = (f32x4){0.f, 0.f, 0.f, 0.f};

    const char* xb = (const char*)xt + (size_t)b * (HW * 1536);
    const int afrag0 = otile * 12 + wm * 3;

    s16x8 ga0, ga1, ga2, ga3, gb0, gb1, gb2, gb3;
    float4 w4a, w4b;

#define WBAR() do { asm volatile("s_waitcnt lgkmcnt(0)" ::: "memory"); \
                    __builtin_amdgcn_s_barrier(); } while (0)
#define ISSUE(G0, G1, G2, G3, W4, qq) do {                                  \
    int nt_ = (qq) / 12, nc_ = (qq) - nt_ * 12;                             \
    W4 = meta_w[nt_ * 64 + bpx];                                            \
    int4 i4_ = meta_i[nt_ * 64 + bpx];                                      \
    const char* bsrc_ = xb + nc_ * 128 + oct * 16;                          \
    G0 = *(const s16x8*)(bsrc_ + i4_.x);                                    \
    G1 = *(const s16x8*)(bsrc_ + i4_.y);                                    \
    G2 = *(const s16x8*)(bsrc_ + i4_.z);                                    \
    G3 = *(const s16x8*)(bsrc_ + i4_.w);                                    \
} while (0)
#define BUILD(G0, G1, G2, G3, W4, BUF) do {                                 \
    u32x4 bw_;                                                              \
    _Pragma("unroll")                                                       \
    for (int e2 = 0; e2 < 4; ++e2) {                                        \
        float v0_ = W4.x * bf2f(G0[2*e2])   + W4.y * bf2f(G1[2*e2])         \
                  + W4.z * bf2f(G2[2*e2])   + W4.w * bf2f(G3[2*e2]);        \
        float v1_ = W4.x * bf2f(G0[2*e2+1]) + W4.y * bf2f(G1[2*e2+1])       \
                  + W4.z * bf2f(G2[2*e2+1]) + W4.w * bf2f(G3[2*e2+1]);      \
        unsigned rr_;                                                       \
        asm("v_cvt_pk_bf16_f32 %0, %1, %2" : "=v"(rr_) : "v"(v0_), "v"(v1_)); \
        bw_[e2] = rr_;                                                      \
    }                                                                       \
    *(u32x4*)&Bs[BUF][bpx][wchunk] = bw_;                                   \
} while (0)
#define MFMA_PHASE_F(P, BUF) do {                                           \
    _Pragma("unroll")                                                       \
    for (int kk = 0; kk < 2; ++kk) {                                        \
        int s_ = 2 * (P) + kk;                                              \
        const s16x8* ap_ = (const s16x8*)(Amat +                            \
            ((size_t)(s_ * 48 + afrag0) * 64 + lane) * 8);                  \
        s16x8 a0_ = ap_[0], a1_ = ap_[64], a2_ = ap_[128];                  \
        int rc_ = ((kk * 4 + q4) ^ (lane & 7)) * 8;                         \
        s16x8 b0_ = *(const s16x8*)&Bs[BUF][wn * 32 + (lane & 15)][rc_];    \
        s16x8 b1_ = *(const s16x8*)&Bs[BUF][wn * 32 + 16 + (lane & 15)][rc_]; \
        acc[0][0] = __builtin_amdgcn_mfma_f32_16x16x32_bf16(a0_, b0_, acc[0][0], 0, 0, 0); \
        acc[0][1] = __builtin_amdgcn_mfma_f32_16x16x32_bf16(a0_, b1_, acc[0][1], 0, 0, 0); \
        acc[1][0] = __builtin_amdgcn_mfma_f32_16x16x32_bf16(a1_, b0_, acc[1][0], 0, 0, 0); \
        acc[1][1] = __builtin_amdgcn_mfma_f32_16x16x32_bf16(a1_, b1_, acc[1][1], 0, 0, 0); \
        acc[2][0] = __builtin_amdgcn_mfma_f32_16x16x32_bf16(a2_, b0_, acc[2][0], 0, 0, 0); \
        acc[2][1] = __builtin_amdgcn_mfma_f32_16x16x32_bf16(a2_, b1_, acc[2][1], 0, 0, 0); \
    }                                                                       \
} while (0)

    ISSUE(ga0, ga1, ga2, ga3, w4a, 0);
    ISSUE(gb0, gb1, gb2, gb3, w4b, 1);
    BUILD(ga0, ga1, ga2, ga3, w4a, 0);
    WBAR();
    for (int pp = 0; pp < 54; ++pp) {
        int pe = 2 * pp;
        if (pp < 53) ISSUE(ga0, ga1, ga2, ga3, w4a, pe + 2);
        MFMA_PHASE_F(pe, 0);
        BUILD(gb0, gb1, gb2, gb3, w4b, 1);
        WBAR();
        int po = pe + 1;
        if (pp < 53) ISSUE(gb0, gb1, gb2, gb3, w4b, po + 2);
        MFMA_PHASE_F(po, 1);
        if (pp < 53) BUILD(ga0, ga1, ga2, ga3, w4a, 0);
        WBAR();
    }
    int pxo = p0 + wn * 32 + (lane & 15);
    int obase = otile * 192 + wm * 48;
#pragma unroll
    for (int f = 0; f < 3; ++f) {
        int orow = obase + f * 16 + ((lane >> 4) << 2);
#pragma unroll
        for (int r = 0; r < 4; ++r) {
            size_t rowoff = ((size_t)(b * 768 + orow + r) << 10);
            y[rowoff + pxo]      = acc[f][0][r];
            y[rowoff + pxo + 16] = acc[f][1][r];
        }
    }
#undef WBAR
#undef ISSUE
#undef BUILD
#undef MFMA_PHASE_F
}

// ---------------------------------------------------------------------------
// Per-channel RAW sums (s1, s2) over (B, H, W).
// ---------------------------------------------------------------------------
__global__ __launch_bounds__(256) void stats_kernel(
    const float* __restrict__ y, float* __restrict__ stats)
{
    int o = blockIdx.x;
    int tid = threadIdx.x;
    float s1 = 0.f, s2 = 0.f;
    for (int i = tid; i < B_N * HW; i += 256) {
        int b = i >> 10, hw = i & 1023;
        float v = y[(((size_t)b * 768 + o) << 10) + hw];
        s1 += v; s2 += v * v;
    }
#pragma unroll
    for (int off = 32; off > 0; off >>= 1) {
        s1 += __shfl_down(s1, off);
        s2 += __shfl_down(s2, off);
    }
    __shared__ float ls1[4], ls2[4];
    int wid = tid >> 6, lane = tid & 63;
    if (lane == 0) { ls1[wid] = s1; ls2[wid] = s2; }
    __syncthreads();
    if (tid == 0) {
        stats[o]       = ls1[0] + ls1[1] + ls1[2] + ls1[3];
        stats[768 + o] = ls2[0] + ls2[1] + ls2[2] + ls2[3];
    }
}

// ---------------------------------------------------------------------------
// normalize (from RAW sums) + exact GELU + residual, in-place on y (= d_out)
// ---------------------------------------------------------------------------
__global__ __launch_bounds__(256) void finalize_kernel(
    const float* __restrict__ x, const float* __restrict__ stats,
    const float* __restrict__ gamma, const float* __restrict__ beta,
    float* __restrict__ y)
{
    const int total4 = B_N * 768 * HW / 4;
    for (int f = blockIdx.x * 256 + threadIdx.x; f < total4;
         f += gridDim.x * 256) {
        int e = f << 2;
        int o = (e >> 10) % 768;
        float s1 = stats[o], s2 = stats[768 + o];
        float mean = s1 * (1.0f / 8192.0f);
        float var  = s2 * (1.0f / 8192.0f) - mean * mean;
        float rstd = 1.0f / sqrtf(var + 1e-5f);
        float ga = gamma[o], be = beta[o];
        float4 v  = ((const float4*)y)[f];
        float4 xv = ((const float4*)x)[f];
        float4 r;
        {
            float yn = (v.x - mean) * rstd * ga + be;
            r.x = xv.x + 0.5f * yn * (1.0f + erff(yn * 0.70710678f));
        }
        {
            float yn = (v.y - mean) * rstd * ga + be;
            r.y = xv.y + 0.5f * yn * (1.0f + erff(yn * 0.70710678f));
        }
        {
            float yn = (v.z - mean) * rstd * ga + be;
            r.z = xv.z + 0.5f * yn * (1.0f + erff(yn * 0.70710678f));
        }
        {
            float yn = (v.w - mean) * rstd * ga + be;
            r.w = xv.w + 0.5f * yn * (1.0f + erff(yn * 0.70710678f));
        }
        ((float4*)y)[f] = r;
    }
}

// ---------------------------------------------------------------------------
extern "C" void kernel_launch(void* const* d_in, const int* in_sizes, int n_in,
                              void* d_out, int out_size, void* d_ws, size_t ws_size,
                              hipStream_t stream)
{
    const float* x        = (const float*)d_in[0];
    const float* proj_w   = (const float*)d_in[1];
    const float* offset_w = (const float*)d_in[3];
    const float* offset_b = (const float*)d_in[4];
    const float* mask_w   = (const float*)d_in[5];
    const float* mask_b   = (const float*)d_in[6];
    const float* gamma    = (const float*)d_in[7];
    const float* beta     = (const float*)d_in[8];

    char* ws = (char*)d_ws;
    float*    offs  = (float*)(ws);                  //   589824 B
    float*    maskb = (float*)(ws + 589824);         //   294912 B
    float*    stats = (float*)(ws + 884736);         //     6144 B
    ushort_t* A     = (ushort_t*)(ws + 890880);      // 10616832 B
    ushort_t* A2    = (ushort_t*)(ws + 11507712);    //   442368 B
    ushort_t* xt    = (ushort_t*)(ws + 11950080);    // 12582912 B
    ushort_t* Bp    = (ushort_t*)(ws + 24532992);    // 113246208 B (if fits)
    float* y = (float*)d_out;

    const size_t NEED_SPLIT = 24532992ull + 113246208ull;   // ~137.8 MB

    prepack_all<<<2220, 256, 0, stream>>>(x, xt, proj_w, A, offset_w, mask_w, A2);
    offmask_mfma<<<256, 1024, 0, stream>>>(xt, A2, offset_b, mask_b, offs, maskb);

    if (ws_size >= NEED_SPLIT) {
        sample_pack<<<512, 512, 0, stream>>>(xt, offs, maskb, Bp);
        deform_gemm_lds<<<512, 512, 0, stream>>>(A, Bp, y);
    } else {
        deform_mfma_fused<<<512, 512, 0, stream>>>(xt, A, offs, maskb, y);
    }

    stats_kernel<<<768, 256, 0, stream>>>(y, stats);
    finalize_kernel<<<2048, 256, 0, stream>>>(x, stats, gamma, beta, y);
}

// Round 19
// 219.253 us; speedup vs baseline: 1.0324x; 1.0324x over previous
//
#include <hip/hip_runtime.h>
#include <math.h>

typedef __attribute__((ext_vector_type(4))) float f32x4;
typedef __attribute__((ext_vector_type(8))) short s16x8;
typedef __attribute__((ext_vector_type(4))) unsigned int u32x4;
typedef unsigned short ushort_t;

#define HW   1024
#define C_IN 768
#define B_N  8

__device__ inline ushort_t f2bf(float f) {
    unsigned u = __builtin_bit_cast(unsigned, f);
    unsigned r = u + 0x7FFFu + ((u >> 16) & 1u);
    return (ushort_t)(r >> 16);
}
__device__ inline float bf2f(short s) {
    return __builtin_bit_cast(float, ((unsigned)(ushort_t)s) << 16);
}
__device__ inline void glds16(const void* g, void* l) {
    __builtin_amdgcn_global_load_lds(
        (const __attribute__((address_space(1))) unsigned*)g,
        (__attribute__((address_space(3))) unsigned*)l, 16, 0, 0);
}

// ---------------------------------------------------------------------------
// Fused prepack: [0,1536) xt transpose; [1536,2112) proj A-frags; [2112,2220)
// offset/mask A-frags. One launch instead of three (saved ~19 us in R18).
// ---------------------------------------------------------------------------
__global__ __launch_bounds__(256) void prepack_all(
    const float* __restrict__ x, ushort_t* __restrict__ xt,
    const float* __restrict__ pw, ushort_t* __restrict__ A,
    const float* __restrict__ offw, const float* __restrict__ mskw,
    ushort_t* __restrict__ A2)
{
    __shared__ ushort_t sh[9344];          // 18688 B, shared by branches
    int bid = blockIdx.x;
    int t = threadIdx.x;

    if (bid < 1536) {                      // ---- xt transpose ----
        ushort_t (*tile)[66] = (ushort_t (*)[66])sh;
        int b  = bid / 192;
        int r  = bid % 192;
        int cg = r / 16, pg = r % 16;
        int c0 = cg * 64, p0 = pg * 64;
#pragma unroll
        for (int i = 0; i < 16; ++i) {
            int idx = t + i * 256;
            int cr = idx >> 6, col = idx & 63;
            tile[cr][col] = f2bf(x[(((size_t)b * C_IN + c0 + cr) << 10) + p0 + col]);
        }
        __syncthreads();
#pragma unroll
        for (int i = 0; i < 16; ++i) {
            int idx = t + i * 256;
            int pr = idx >> 6, col = idx & 63;
            xt[((size_t)(b << 10) + p0 + pr) * C_IN + c0 + col] = tile[col][pr];
        }
    } else if (bid < 2112) {               // ---- proj_w A-frags ----
        ushort_t (*tile)[584] = (ushort_t (*)[584])sh;
        int pb = bid - 1536;               // 48 mf x 12 cblk
        int mf = pb / 12, cblk = pb - mf * 12;
        const float* src = pw + (size_t)mf * 16 * 6912 + cblk * 576;
#pragma unroll
        for (int i = 0; i < 36; ++i) {
            int f = i * 256 + t;
            int orow = f / 576, col = f - orow * 576;
            tile[orow][col] = f2bf(src[(size_t)orow * 6912 + col]);
        }
        __syncthreads();
        int lane = t & 63, fi0 = t >> 6;
        for (int it = 0; it < 5; ++it) {
            int fidx = it * 4 + fi0;       // 18 frags: tap*2 + half
            if (fidx < 18) {
                int tap = fidx >> 1, half = fidx & 1;
                int s = tap * 24 + cblk * 2 + half;
                int cl0 = half * 32 + ((lane >> 4) << 3);
                s16x8 pk;
#pragma unroll
                for (int e = 0; e < 8; ++e)
                    pk[e] = (short)tile[lane & 15][(cl0 + e) * 9 + tap];
                *(s16x8*)(A + ((size_t)(s * 48 + mf) * 64 + lane) * 8) = pk;
            }
        }
    } else {                               // ---- offset/mask A-frags ----
        int tt = (bid - 2112) * 256 + t;   // 216*2*64 threads
        int lane = tt & 63;
        int smi  = tt >> 6;
        int s  = smi >> 1, mf = smi & 1;
        int oc = mf * 16 + (lane & 15);
        int k0 = s * 32 + ((lane >> 4) << 3);
        int tap = k0 / 768;
        int c   = k0 - tap * 768;
        s16x8 pk;
#pragma unroll
        for (int e = 0; e < 8; ++e) pk[e] = 0;
        if (oc < 27) {
            const float* src = (oc < 18)
                ? offw + ((size_t)oc        * 768 + c) * 9 + tap
                : mskw + ((size_t)(oc - 18) * 768 + c) * 9 + tap;
#pragma unroll
            for (int e = 0; e < 8; ++e) pk[e] = (short)f2bf(src[e * 9]);
        }
        *(s16x8*)(A2 + (size_t)smi * 512 + lane * 8) = pk;
    }
}

// ---------------------------------------------------------------------------
// Offset/mask conv: LDS-free MFMA GEMM, 4-way K-split (16 waves, no in-loop
// barriers; single end reduction).
// ---------------------------------------------------------------------------
__global__ __launch_bounds__(1024) void offmask_mfma(
    const ushort_t* __restrict__ xt, const ushort_t* __restrict__ A2,
    const float* __restrict__ offb, const float* __restrict__ mbias,
    float* __restrict__ offs, float* __restrict__ maskb)
{
    __shared__ f32x4 red[16][64];
    int bid = blockIdx.x;               // b*32 + pt
    int b = bid >> 5, pt = bid & 31;
    int p0 = pt << 5;
    int t = threadIdx.x, lane = t & 63, wv = t >> 6;
    int kq = wv >> 2, quad = wv & 3;
    int mf = quad >> 1, nf = quad & 1;
    int q = lane >> 4;
    int px = p0 + nf * 16 + (lane & 15);
    int h = px >> 5, w = px & 31;
    const char* xb = (const char*)xt + (size_t)b * (HW * 1536);
    f32x4 acc = (f32x4){0.f, 0.f, 0.f, 0.f};

    int s0 = kq * 54;
    for (int s = s0; s < s0 + 54; ++s) {
        int tap = s / 24, cs = s - tap * 24;
        int yy = h + tap / 3 - 1, xx = w + tap % 3 - 1;
        bool ok = (yy >= 0 && yy < 32 && xx >= 0 && xx < 32);
        int pos = ok ? (yy * 32 + xx) : 0;
        const char* bp = xb + (size_t)pos * 1536 + cs * 64 + q * 16;
        s16x8 bf;
        if (ok) bf = *(const s16x8*)bp;
        else    bf = (s16x8){0, 0, 0, 0, 0, 0, 0, 0};
        s16x8 af = *(const s16x8*)(A2 + ((size_t)(s * 2 + mf) * 64 + lane) * 8);
        acc = __builtin_amdgcn_mfma_f32_16x16x32_bf16(af, bf, acc, 0, 0, 0);
    }
    red[wv][lane] = acc;
    __syncthreads();
    if (wv < 4) {
        f32x4 r1 = red[wv + 4][lane];
        f32x4 r2 = red[wv + 8][lane];
        f32x4 r3 = red[wv + 12][lane];
        acc += r1; acc += r2; acc += r3;
#pragma unroll
        for (int r = 0; r < 4; ++r) {
            int oc = mf * 16 + ((lane >> 4) << 2) + r;
            if (oc < 18) {
                float v = acc[r] + offb[oc];
                v = fminf(fmaxf(v, -8.f), 8.f);        // max_off = 32//4
                offs[((b * 18 + oc) << 10) + px] = v;
            } else if (oc < 27) {
                float v = acc[r] + mbias[oc - 18];
                maskb[((b * 9 + oc - 18) << 10) + px] = 2.f / (1.f + expf(-v));
            }
        }
    }
}

// ---------------------------------------------------------------------------
// Split kernel 1: build the bilinear-sampled tensor ONCE (1x replication),
// directly in MFMA B-fragment layout. b = bid&7 -> XCD keeps xt slab L2-local.
// ---------------------------------------------------------------------------
__global__ __launch_bounds__(512) void sample_pack(
    const ushort_t* __restrict__ xt,
    const float* __restrict__ offs, const float* __restrict__ maskb,
    ushort_t* __restrict__ Bp)
{
    __shared__ float4 mw[9][16];
    __shared__ int4   mi[9][16];
    int bid = blockIdx.x;                 // pxg*8 + b  (b = XCD slab)
    int b = bid & 7, pxg = bid >> 3;
    int px0 = pxg << 4;
    int t = threadIdx.x;

    if (t < 144) {
        int tap = t >> 4, pxl = t & 15;
        int px = px0 + pxl, h = px >> 5, w = px & 31;
        float dy = offs[((b * 18 + 2 * tap) << 10) + px];
        float dx = offs[((b * 18 + 2 * tap + 1) << 10) + px];
        float m  = maskb[((b * 9 + tap) << 10) + px];
        float ys = dy + (float)(h + tap / 3 - 1);
        float xs = dx + (float)(w + tap % 3 - 1);
        float fy = floorf(ys), fx = floorf(xs);
        float wy = ys - fy, wx = xs - fx;
        int iy0 = (int)fy, ix0 = (int)fx;
        int iy1 = iy0 + 1, ix1 = ix0 + 1;
        float vy0 = (iy0 >= 0 && iy0 < 32) ? 1.f : 0.f;
        float vy1 = (iy1 >= 0 && iy1 < 32) ? 1.f : 0.f;
        float vx0 = (ix0 >= 0 && ix0 < 32) ? 1.f : 0.f;
        float vx1 = (ix1 >= 0 && ix1 < 32) ? 1.f : 0.f;
        int cy0 = min(max(iy0, 0), 31), cx0 = min(max(ix0, 0), 31);
        int cy1 = min(max(iy1, 0), 31), cx1 = min(max(ix1, 0), 31);
        float4 wv4;
        wv4.x = (1.f - wy) * (1.f - wx) * m * vy0 * vx0;
        wv4.y = (1.f - wy) * wx         * m * vy0 * vx1;
        wv4.z = wy         * (1.f - wx) * m * vy1 * vx0;
        wv4.w = wy         * wx         * m * vy1 * vx1;
        mw[tap][pxl] = wv4;
        mi[tap][pxl] = make_int4((cy0 * 32 + cx0) * 1536, (cy0 * 32 + cx1) * 1536,
                                 (cy1 * 32 + cx0) * 1536, (cy1 * 32 + cx1) * 1536);
    }
    __syncthreads();

    int lane = t & 63, wv = t >> 6;
    int pxl = lane & 15, ko = lane >> 4;
    const char* xb = (const char*)xt + (size_t)b * (HW * 1536);

    for (int s = wv; s < 216; s += 8) {
        int tap = s / 24, cq = s - tap * 24;
        float4 w4 = mw[tap][pxl];
        int4  i4 = mi[tap][pxl];
        const char* base = xb + cq * 64 + ko * 16;
        s16x8 g0 = *(const s16x8*)(base + i4.x);
        s16x8 g1 = *(const s16x8*)(base + i4.y);
        s16x8 g2 = *(const s16x8*)(base + i4.z);
        s16x8 g3 = *(const s16x8*)(base + i4.w);
        u32x4 bw;
#pragma unroll
        for (int e2 = 0; e2 < 4; ++e2) {
            float v0 = w4.x * bf2f(g0[2 * e2])     + w4.y * bf2f(g1[2 * e2])
                     + w4.z * bf2f(g2[2 * e2])     + w4.w * bf2f(g3[2 * e2]);
            float v1 = w4.x * bf2f(g0[2 * e2 + 1]) + w4.y * bf2f(g1[2 * e2 + 1])
                     + w4.z * bf2f(g2[2 * e2 + 1]) + w4.w * bf2f(g3[2 * e2 + 1]);
            unsigned rr;
            asm("v_cvt_pk_bf16_f32 %0, %1, %2" : "=v"(rr) : "v"(v0), "v"(v1));
            bw[e2] = rr;
        }
        *(u32x4*)(Bp + ((size_t)(s * 8 + b) * 64 + pxg) * 512 + lane * 8) = bw;
    }
}

// ---------------------------------------------------------------------------
// Split kernel 2: the R12/R17-proven LDS-staged frag GEMM (96 us, MfmaUtil
// ~43%). Block 192(o) x 64(px), K-phase 64, 108 phases. 512 thr / 8 waves
// (4wm x 2wn), 12 MFMA/wave/phase. Per phase: stage 24KB A + 8KB B via
// global_load_lds, double-buffered 64KB LDS (2 blk/CU), STAGE(p+1) ->
// MFMA(p) -> vmcnt(0)+lgkmcnt(0) -> barrier.
// ---------------------------------------------------------------------------
__global__ __launch_bounds__(512, 4) void deform_gemm_lds(
    const ushort_t* __restrict__ Amat, const ushort_t* __restrict__ Bp,
    float* __restrict__ y)
{
    __shared__ __align__(16) char Sbuf[2][32768];

    int id = blockIdx.x;                  // 512 = 8b x 16pxt x 4otile
    int b = id & 7;                       // b == XCD slab locality
    int pxt = (id >> 3) & 15;
    int otile = id >> 7;
    int p0 = pxt << 6;
    int t = threadIdx.x, lane = t & 63, wv = t >> 6;
    int wm = wv >> 1, wn = wv & 1;

    f32x4 acc[3][2];
#pragma unroll
    for (int f = 0; f < 3; ++f)
#pragma unroll
        for (int n = 0; n < 2; ++n) acc[f][n] = (f32x4){0.f, 0.f, 0.f, 0.f};

#define STAGE(BUF, P) do {                                                  \
    int s0_ = 2 * (P);                                                      \
    _Pragma("unroll")                                                       \
    for (int i_ = 0; i_ < 4; ++i_) {                                        \
        int c_ = wv * 4 + i_;                                               \
        const char* src_;                                                   \
        if (c_ < 24) {                                                      \
            int kk_ = c_ / 12, f_ = c_ - kk_ * 12;                          \
            src_ = (const char*)Amat +                                      \
                (((size_t)(s0_ + kk_) * 48 + otile * 12 + f_) << 10);       \
        } else {                                                            \
            int d_ = c_ - 24; int kk_ = d_ >> 2, pg_ = d_ & 3;              \
            src_ = (const char*)Bp +                                        \
                (((size_t)((s0_ + kk_) * 8 + b) * 64 + pxt * 4 + pg_) << 10); \
        }                                                                   \
        glds16(src_ + lane * 16, &Sbuf[BUF][c_ << 10]);                     \
    }                                                                       \
} while (0)

#define MFMA_PHASE(BUF) do {                                                \
    _Pragma("unroll")                                                       \
    for (int kk_ = 0; kk_ < 2; ++kk_) {                                     \
        const char* ab_ = &Sbuf[BUF][(kk_ * 12 + wm * 3) << 10] + lane * 16; \
        s16x8 a0_ = *(const s16x8*)(ab_);                                   \
        s16x8 a1_ = *(const s16x8*)(ab_ + 1024);                            \
        s16x8 a2_ = *(const s16x8*)(ab_ + 2048);                            \
        const char* bb_ = &Sbuf[BUF][(24 + kk_ * 4 + wn * 2) << 10] + lane * 16; \
        s16x8 b0_ = *(const s16x8*)(bb_);                                   \
        s16x8 b1_ = *(const s16x8*)(bb_ + 1024);                            \
        acc[0][0] = __builtin_amdgcn_mfma_f32_16x16x32_bf16(a0_, b0_, acc[0][0], 0, 0, 0); \
        acc[0][1] = __builtin_amdgcn_mfma_f32_16x16x32_bf16(a0_, b1_, acc[0][1], 0, 0, 0); \
        acc[1][0] = __builtin_amdgcn_mfma_f32_16x16x32_bf16(a1_, b0_, acc[1][0], 0, 0, 0); \
        acc[1][1] = __builtin_amdgcn_mfma_f32_16x16x32_bf16(a1_, b1_, acc[1][1], 0, 0, 0); \
        acc[2][0] = __builtin_amdgcn_mfma_f32_16x16x32_bf16(a2_, b0_, acc[2][0], 0, 0, 0); \
        acc[2][1] = __builtin_amdgcn_mfma_f32_16x16x32_bf16(a2_, b1_, acc[2][1], 0, 0, 0); \
    }                                                                       \
} while (0)

    // prologue
    STAGE(0, 0);
    asm volatile("s_waitcnt vmcnt(0)" ::: "memory");
    __builtin_amdgcn_s_barrier();

    for (int p = 0; p < 108; ++p) {
        int buf = p & 1;
        if (p + 1 < 108) STAGE(buf ^ 1, p + 1);
        __builtin_amdgcn_s_setprio(1);
        MFMA_PHASE(buf);
        __builtin_amdgcn_s_setprio(0);
        asm volatile("s_waitcnt vmcnt(0) lgkmcnt(0)" ::: "memory");
        __builtin_amdgcn_s_barrier();
    }

    // epilogue (no bias: per-channel bias cancels in batch-norm)
    int pxo = p0 + wn * 32 + (lane & 15);
    int obase = otile * 192 + wm * 48;
#pragma unroll
    for (int f = 0; f < 3; ++f) {
        int orow = obase + f * 16 + ((lane >> 4) << 2);
#pragma unroll
        for (int r = 0; r < 4; ++r) {
            size_t rowoff = ((size_t)(b * 768 + orow + r) << 10);
            y[rowoff + pxo]      = acc[f][0][r];
            y[rowoff + pxo + 16] = acc[f][1][r];
        }
    }
#undef STAGE
#undef MFMA_PHASE
}

// ---------------------------------------------------------------------------
// FALLBACK (small ws): fused deform GEMM — the proven R5 structure.
// ---------------------------------------------------------------------------
__global__ __launch_bounds__(512, 4) void deform_mfma_fused(
    const ushort_t* __restrict__ xt, const ushort_t* __restrict__ Amat,
    const float* __restrict__ offs, const float* __restrict__ maskb,
    float* __restrict__ y)
{
    __shared__ float4 meta_w[576];
    __shared__ int4   meta_i[576];
    __shared__ __align__(16) ushort_t Bs[2][64][64];

    int id = blockIdx.x;
    int b = id & 7;
    int pxt = (id >> 3) & 15;
    int otile = id >> 7;
    int p0 = pxt << 6;
    int t = threadIdx.x, lane = t & 63, wv = t >> 6;
    int wm = wv >> 1, wn = wv & 1;
    int q4 = lane >> 4;

    int bpx = wv * 8 + (lane >> 3);
    int oct = lane & 7;
    const int wchunk = (oct ^ (bpx & 7)) * 8;

    for (int i = t; i < 576; i += 512) {
        int k = i >> 6, j = i & 63;
        int hw = p0 + j, h = hw >> 5, w = hw & 31;
        float dy = offs[((b * 18 + 2 * k) << 10) + hw];
        float dx = offs[((b * 18 + 2 * k + 1) << 10) + hw];
        float m  = maskb[((b * 9 + k) << 10) + hw];
        float ys = dy + (float)(h + k / 3 - 1);
        float xs = dx + (float)(w + k % 3 - 1);
        float fy = floorf(ys), fx = floorf(xs);
        float wy = ys - fy, wx = xs - fx;
        int iy0 = (int)fy, ix0 = (int)fx;
        int iy1 = iy0 + 1, ix1 = ix0 + 1;
        float vy0 = (iy0 >= 0 && iy0 < 32) ? 1.f : 0.f;
        float vy1 = (iy1 >= 0 && iy1 < 32) ? 1.f : 0.f;
        float vx0 = (ix0 >= 0 && ix0 < 32) ? 1.f : 0.f;
        float vx1 = (ix1 >= 0 && ix1 < 32) ? 1.f : 0.f;
        int cy0 = min(max(iy0, 0), 31), cx0 = min(max(ix0, 0), 31);
        int cy1 = min(max(iy1, 0), 31), cx1 = min(max(ix1, 0), 31);
        float4 wv4;
        wv4.x = (1.f - wy) * (1.f - wx) * m * vy0 * vx0;
        wv4.y = (1.f - wy) * wx         * m * vy0 * vx1;
        wv4.z = wy         * (1.f - wx) * m * vy1 * vx0;
        wv4.w = wy         * wx         * m * vy1 * vx1;
        meta_w[i] = wv4;
        meta_i[i] = make_int4((cy0 * 32 + cx0) * 1536, (cy0 * 32 + cx1) * 1536,
                              (cy1 * 32 + cx0) * 1536, (cy1 * 32 + cx1) * 1536);
    }
    asm volatile("s_waitcnt lgkmcnt(0)" ::: "memory");
    __builtin_amdgcn_s_barrier();

    f32x4 acc[3][2];
#pragma unroll
    for (int f = 0; f < 3; ++f)
#pragma unroll
        for (int n = 0; n < 2; ++n) acc[f][n] = (f32x4){0.f, 0.f, 0.f, 0.f};

    const char* xb = (const char*)xt + (size_t)b * (HW * 1536);
    const int afrag0 = otile * 12 + wm * 3;

    s16x8 ga0, ga1, ga2, ga3, gb0, gb1, gb2, gb3;
    float4 w4a, w4b;

#define WBAR() do { asm volatile("s_waitcnt lgkmcnt(0)" ::: "memory"); \
                    __builtin_amdgcn_s_barrier(); } while (0)
#define ISSUE(G0, G1, G2, G3, W4, qq) do {                                  \
    int nt_ = (qq) / 12, nc_ = (qq) - nt_ * 12;                             \
    W4 = meta_w[nt_ * 64 + bpx];                                            \
    int4 i4_ = meta_i[nt_ * 64 + bpx];                                      \
    const char* bsrc_ = xb + nc_ * 128 + oct * 16;                          \
    G0 = *(const s16x8*)(bsrc_ + i4_.x);                                    \
    G1 = *(const s16x8*)(bsrc_ + i4_.y);                                    \
    G2 = *(const s16x8*)(bsrc_ + i4_.z);                                    \
    G3 = *(const s16x8*)(bsrc_ + i4_.w);                                    \
} while (0)
#define BUILD(G0, G1, G2, G3, W4, BUF) do {                                 \
    u32x4 bw_;                                                              \
    _Pragma("unroll")                                                       \
    for (int e2 = 0; e2 < 4; ++e2) {                                        \
        float v0_ = W4.x * bf2f(G0[2*e2])   + W4.y * bf2f(G1[2*e2])         \
                  + W4.z * bf2f(G2[2*e2])   + W4.w * bf2f(G3[2*e2]);        \
        float v1_ = W4.x * bf2f(G0[2*e2+1]) + W4.y * bf2f(G1[2*e2+1])       \
                  + W4.z * bf2f(G2[2*e2+1]) + W4.w * bf2f(G3[2*e2+1]);      \
        unsigned rr_;                                                       \
        asm("v_cvt_pk_bf16_f32 %0, %1, %2" : "=v"(rr_) : "v"(v0_), "v"(v1_)); \
        bw_[e2] = rr_;                                                      \
    }                                                                       \
    *(u32x4*)&Bs[BUF][bpx][wchunk] = bw_;                                   \
} while (0)
#define MFMA_PHASE_F(P, BUF) do {                                           \
    _Pragma("unroll")                                                       \
    for (int kk = 0; kk < 2; ++kk) {                                        \
        int s_ = 2 * (P) + kk;                                              \
        const s16x8* ap_ = (const s16x8*)(Amat +                            \
            ((size_t)(s_ * 48 + afrag0) * 64 + lane) * 8);                  \
        s16x8 a0_ = ap_[0], a1_ = ap_[64], a2_ = ap_[128];                  \
        int rc_ = ((kk * 4 + q4) ^ (lane & 7)) * 8;                         \
        s16x8 b0_ = *(const s16x8*)&Bs[BUF][wn * 32 + (lane & 15)][rc_];    \
        s16x8 b1_ = *(const s16x8*)&Bs[BUF][wn * 32 + 16 + (lane & 15)][rc_]; \
        acc[0][0] = __builtin_amdgcn_mfma_f32_16x16x32_bf16(a0_, b0_, acc[0][0], 0, 0, 0); \
        acc[0][1] = __builtin_amdgcn_mfma_f32_16x16x32_bf16(a0_, b1_, acc[0][1], 0, 0, 0); \
        acc[1][0] = __builtin_amdgcn_mfma_f32_16x16x32_bf16(a1_, b0_, acc[1][0], 0, 0, 0); \
        acc[1][1] = __builtin_amdgcn_mfma_f32_16x16x32_bf16(a1_, b1_, acc[1][1], 0, 0, 0); \
        acc[2][0] = __builtin_amdgcn_mfma_f32_16x16x32_bf16(a2_, b0_, acc[2][0], 0, 0, 0); \
        acc[2][1] = __builtin_amdgcn_mfma_f32_16x16x32_bf16(a2_, b1_, acc[2][1], 0, 0, 0); \
    }                                                                       \
} while (0)

    ISSUE(ga0, ga1, ga2, ga3, w4a, 0);
    ISSUE(gb0, gb1, gb2, gb3, w4b, 1);
    BUILD(ga0, ga1, ga2, ga3, w4a, 0);
    WBAR();
    for (int pp = 0; pp < 54; ++pp) {
        int pe = 2 * pp;
        if (pp < 53) ISSUE(ga0, ga1, ga2, ga3, w4a, pe + 2);
        MFMA_PHASE_F(pe, 0);
        BUILD(gb0, gb1, gb2, gb3, w4b, 1);
        WBAR();
        int po = pe + 1;
        if (pp < 53) ISSUE(gb0, gb1, gb2, gb3, w4b, po + 2);
        MFMA_PHASE_F(po, 1);
        if (pp < 53) BUILD(ga0, ga1, ga2, ga3, w4a, 0);
        WBAR();
    }
    int pxo = p0 + wn * 32 + (lane & 15);
    int obase = otile * 192 + wm * 48;
#pragma unroll
    for (int f = 0; f < 3; ++f) {
        int orow = obase + f * 16 + ((lane >> 4) << 2);
#pragma unroll
        for (int r = 0; r < 4; ++r) {
            size_t rowoff = ((size_t)(b * 768 + orow + r) << 10);
            y[rowoff + pxo]      = acc[f][0][r];
            y[rowoff + pxo + 16] = acc[f][1][r];
        }
    }
#undef WBAR
#undef ISSUE
#undef BUILD
#undef MFMA_PHASE_F
}

// ---------------------------------------------------------------------------
// Per-channel RAW sums (s1, s2) over (B, H, W).
// ---------------------------------------------------------------------------
__global__ __launch_bounds__(256) void stats_kernel(
    const float* __restrict__ y, float* __restrict__ stats)
{
    int o = blockIdx.x;
    int tid = threadIdx.x;
    float s1 = 0.f, s2 = 0.f;
    for (int i = tid; i < B_N * HW; i += 256) {
        int b = i >> 10, hw = i & 1023;
        float v = y[(((size_t)b * 768 + o) << 10) + hw];
        s1 += v; s2 += v * v;
    }
#pragma unroll
    for (int off = 32; off > 0; off >>= 1) {
        s1 += __shfl_down(s1, off);
        s2 += __shfl_down(s2, off);
    }
    __shared__ float ls1[4], ls2[4];
    int wid = tid >> 6, lane = tid & 63;
    if (lane == 0) { ls1[wid] = s1; ls2[wid] = s2; }
    __syncthreads();
    if (tid == 0) {
        stats[o]       = ls1[0] + ls1[1] + ls1[2] + ls1[3];
        stats[768 + o] = ls2[0] + ls2[1] + ls2[2] + ls2[3];
    }
}

// ---------------------------------------------------------------------------
// normalize (from RAW sums) + exact GELU + residual, in-place on y (= d_out)
// ---------------------------------------------------------------------------
__global__ __launch_bounds__(256) void finalize_kernel(
    const float* __restrict__ x, const float* __restrict__ stats,
    const float* __restrict__ gamma, const float* __restrict__ beta,
    float* __restrict__ y)
{
    const int total4 = B_N * 768 * HW / 4;
    for (int f = blockIdx.x * 256 + threadIdx.x; f < total4;
         f += gridDim.x * 256) {
        int e = f << 2;
        int o = (e >> 10) % 768;
        float s1 = stats[o], s2 = stats[768 + o];
        float mean = s1 * (1.0f / 8192.0f);
        float var  = s2 * (1.0f / 8192.0f) - mean * mean;
        float rstd = 1.0f / sqrtf(var + 1e-5f);
        float ga = gamma[o], be = beta[o];
        float4 v  = ((const float4*)y)[f];
        float4 xv = ((const float4*)x)[f];
        float4 r;
        {
            float yn = (v.x - mean) * rstd * ga + be;
            r.x = xv.x + 0.5f * yn * (1.0f + erff(yn * 0.70710678f));
        }
        {
            float yn = (v.y - mean) * rstd * ga + be;
            r.y = xv.y + 0.5f * yn * (1.0f + erff(yn * 0.70710678f));
        }
        {
            float yn = (v.z - mean) * rstd * ga + be;
            r.z = xv.z + 0.5f * yn * (1.0f + erff(yn * 0.70710678f));
        }
        {
            float yn = (v.w - mean) * rstd * ga + be;
            r.w = xv.w + 0.5f * yn * (1.0f + erff(yn * 0.70710678f));
        }
        ((float4*)y)[f] = r;
    }
}

// ---------------------------------------------------------------------------
extern "C" void kernel_launch(void* const* d_in, const int* in_sizes, int n_in,
                              void* d_out, int out_size, void* d_ws, size_t ws_size,
                              hipStream_t stream)
{
    const float* x        = (const float*)d_in[0];
    const float* proj_w   = (const float*)d_in[1];
    const float* offset_w = (const float*)d_in[3];
    const float* offset_b = (const float*)d_in[4];
    const float* mask_w   = (const float*)d_in[5];
    const float* mask_b   = (const float*)d_in[6];
    const float* gamma    = (const float*)d_in[7];
    const float* beta     = (const float*)d_in[8];

    char* ws = (char*)d_ws;
    float*    offs  = (float*)(ws);                  //   589824 B
    float*    maskb = (float*)(ws + 589824);         //   294912 B
    float*    stats = (float*)(ws + 884736);         //     6144 B
    ushort_t* A     = (ushort_t*)(ws + 890880);      // 10616832 B
    ushort_t* A2    = (ushort_t*)(ws + 11507712);    //   442368 B
    ushort_t* xt    = (ushort_t*)(ws + 11950080);    // 12582912 B
    ushort_t* Bp    = (ushort_t*)(ws + 24532992);    // 113246208 B (if fits)
    float* y = (float*)d_out;

    const size_t NEED_SPLIT = 24532992ull + 113246208ull;   // ~137.8 MB

    prepack_all<<<2220, 256, 0, stream>>>(x, xt, proj_w, A, offset_w, mask_w, A2);
    offmask_mfma<<<256, 1024, 0, stream>>>(xt, A2, offset_b, mask_b, offs, maskb);

    if (ws_size >= NEED_SPLIT) {
        sample_pack<<<512, 512, 0, stream>>>(xt, offs, maskb, Bp);
        deform_gemm_lds<<<512, 512, 0, stream>>>(A, Bp, y);
    } else {
        deform_mfma_fused<<<512, 512, 0, stream>>>(xt, A, offs, maskb, y);
    }

    stats_kernel<<<768, 256, 0, stream>>>(y, stats);
    finalize_kernel<<<2048, 256, 0, stream>>>(x, stats, gamma, beta, y);
}